// Round 6
// baseline (136.292 us; speedup 1.0000x reference)
//
#include <hip/hip_runtime.h>
#include <math.h>

#define N_NODES 50000
#define DEG 32
#define WIDTH 128
#define BATCH 4096
#define EPS 1e-12f

typedef __attribute__((ext_vector_type(8))) short short8;           // 8 bf16
typedef __attribute__((ext_vector_type(4))) float f32x4;            // MFMA acc
typedef unsigned short u16;

__device__ __forceinline__ u16 f2bf(float f) {
    unsigned x;
    __builtin_memcpy(&x, &f, 4);
    unsigned r = (x + 0x7fff + ((x >> 16) & 1)) >> 16;  // RNE
    return (u16)r;
}
__device__ __forceinline__ unsigned pkmax_u16(unsigned a, unsigned b) {
    unsigned lo = (a & 0xffffu) > (b & 0xffffu) ? (a & 0xffffu) : (b & 0xffffu);
    unsigned hi = (a >> 16) > (b >> 16) ? (a >> 16) : (b >> 16);
    return lo | (hi << 16);
}

// ---------------- prep: inv=-1, weights->bf16, packed relu(b_agg) ----------------
__global__ void prep_k(const float* __restrict__ W_agg, const float* __restrict__ W_lin,
                       const float* __restrict__ b_agg, int* __restrict__ inv,
                       u16* __restrict__ Wab, u16* __restrict__ Wlb,
                       unsigned* __restrict__ rbap) {
    int i = blockIdx.x * 256 + threadIdx.x;
    if (i < 50048) inv[i] = -1;
    int j = i - 50048;
    if (j >= 0 && j < 16384) Wab[j] = f2bf(W_agg[j]);
    int k = i - (50048 + 16384);
    if (k >= 0 && k < 32768) Wlb[k] = f2bf(W_lin[k]);
    if (i < 64) {
        float a = b_agg[2 * i], b = b_agg[2 * i + 1];
        a = a > 0.f ? a : 0.f;
        b = b > 0.f ? b : 0.f;
        rbap[i] = (unsigned)f2bf(a) | ((unsigned)f2bf(b) << 16);
    }
}

// ---------------- head: scatter inv; M0b(bf16)=relu(feats@Wagg.T+b_agg); S(f32)=feats@Wself.T
// 256 blocks x 512 thr (8 waves); block owns 16 rows; wave w owns cols w*16..+15.
__global__ __launch_bounds__(512) void head_k(
    const float* __restrict__ feats, const u16* __restrict__ Wab, const u16* __restrict__ Wlb,
    const float* __restrict__ b_agg, const int* __restrict__ node_idx, int* __restrict__ inv,
    u16* __restrict__ M0b, float* __restrict__ S) {
    int tid = threadIdx.x;
    int gid = blockIdx.x * 512 + tid;
    if (gid < BATCH) atomicMax(&inv[node_idx[gid]], gid);  // last-write-wins scatter

    int w = tid >> 6, l = tid & 63, li = l & 15, kq = l >> 4;
    int r0 = blockIdx.x * 16;
    int arow = r0 + li;
    int col = w * 16 + li;

    f32x4 am = (f32x4){0,0,0,0}, as = (f32x4){0,0,0,0};
#pragma unroll
    for (int kk = 0; kk < 4; ++kk) {
        float4 a0 = *(const float4*)(feats + (size_t)arow * 128 + kk * 32 + kq * 8);
        float4 a1 = *(const float4*)(feats + (size_t)arow * 128 + kk * 32 + kq * 8 + 4);
        short8 a;
        a[0] = (short)f2bf(a0.x); a[1] = (short)f2bf(a0.y);
        a[2] = (short)f2bf(a0.z); a[3] = (short)f2bf(a0.w);
        a[4] = (short)f2bf(a1.x); a[5] = (short)f2bf(a1.y);
        a[6] = (short)f2bf(a1.z); a[7] = (short)f2bf(a1.w);
        short8 bm = *(const short8*)(Wab + (size_t)col * 128 + kk * 32 + kq * 8);
        am = __builtin_amdgcn_mfma_f32_16x16x32_bf16(a, bm, am, 0, 0, 0);
        short8 bs = *(const short8*)(Wlb + (size_t)col * 256 + kk * 32 + kq * 8);
        as = __builtin_amdgcn_mfma_f32_16x16x32_bf16(a, bs, as, 0, 0, 0);
    }

    float ba = b_agg[col];
#pragma unroll
    for (int r = 0; r < 4; ++r) {
        int grow = r0 + kq * 4 + r;
        float t = am[r] + ba;
        t = t > 0.f ? t : 0.f;               // +0-safe relu (feeds u16-max)
        M0b[(size_t)grow * 128 + col] = f2bf(t);
        S[(size_t)grow * 128 + col] = as[r];
    }
}

// ---------------- agg1: one WAVE per node; wave-uniform list loads; packed u16 max ----------------
// AGG1[n] = max(warm: M0b[inv[nb]], anyCold: relu(b_agg)) in bf16/u16 domain.
__global__ __launch_bounds__(256) void agg1_k(
    const int* __restrict__ nbd, const int* __restrict__ inv,
    const u16* __restrict__ M0b, const unsigned* __restrict__ rbap,
    unsigned* __restrict__ AGG1u) {
    int wid = blockIdx.x * 4 + (threadIdx.x >> 6);   // node id, 12500*4 == 50000 exact
    int lane = threadIdx.x & 63;

    unsigned acc = 0;
    bool anyCold = false;
#pragma unroll
    for (int j = 0; j < DEG; ++j) {
        int bi = inv[nbd[(size_t)wid * DEG + j]];    // wave-uniform (scalar path)
        if (bi < 0) {
            anyCold = true;
        } else {
            unsigned v = *(const unsigned*)(M0b + (size_t)bi * WIDTH + lane * 2);
            acc = pkmax_u16(acc, v);
        }
    }
    if (anyCold) acc = pkmax_u16(acc, rbap[lane]);
    AGG1u[(size_t)wid * 64 + lane] = acc;
}

// ---------------- hop1mm: H1 = norm(relu(AGG1@Wlp.T + S[inv] + b_lin)); M1 = relu(H1@Wagg.T + b_agg)
// 782 blocks x 512 thr = 8 waves: 4 row-groups x 2 col-groups; 64-row tile.
__global__ __launch_bounds__(512) void hop1mm_k(
    const u16* __restrict__ AGG1, const int* __restrict__ inv,
    const float* __restrict__ S, const float* __restrict__ b_lin,
    const float* __restrict__ b_agg,
    const u16* __restrict__ Wlb, const u16* __restrict__ Wab,
    u16* __restrict__ H1g, u16* __restrict__ M1) {
    __shared__ u16 h1t[64 * 136];    // transpose buffer
    __shared__ float pnorm[2 * 64];  // [cg][row64]

    int tid = threadIdx.x;
    int w = tid >> 6, l = tid & 63, li = l & 15, kq = l >> 4;
    int rg = w >> 1, cg = w & 1;
    int row0 = blockIdx.x * 64;
    int lrow = rg * 16 + li;
    int arow = row0 + lrow;
    if (arow > N_NODES - 1) arow = N_NODES - 1;

    short8 af[4];
#pragma unroll
    for (int kk = 0; kk < 4; ++kk)
        af[kk] = *(const short8*)(AGG1 + (size_t)arow * 128 + kk * 32 + kq * 8);

    f32x4 h[4];
#pragma unroll
    for (int n = 0; n < 4; ++n) h[n] = (f32x4){0,0,0,0};
#pragma unroll
    for (int kk = 0; kk < 4; ++kk)
#pragma unroll
        for (int n = 0; n < 4; ++n) {
            int col = cg * 64 + n * 16 + li;
            short8 b = *(const short8*)(Wlb + (size_t)col * 256 + 128 + kk * 32 + kq * 8);
            h[n] = __builtin_amdgcn_mfma_f32_16x16x32_bf16(af[kk], b, h[n], 0, 0, 0);
        }

    float blv[4];
#pragma unroll
    for (int n = 0; n < 4; ++n) blv[n] = b_lin[cg * 64 + n * 16 + li];

    float v[4][4];   // [r][n] static-indexed
    int biA[4];
#pragma unroll
    for (int r = 0; r < 4; ++r) {
        int lr = rg * 16 + kq * 4 + r;
        int grow = row0 + lr;
        int growc = grow < N_NODES ? grow : N_NODES - 1;
        biA[r] = inv[growc];
#pragma unroll
        for (int n = 0; n < 4; ++n) v[r][n] = h[n][r] + blv[n];
        if (biA[r] >= 0) {
#pragma unroll
            for (int n = 0; n < 4; ++n)
                v[r][n] += S[(size_t)biA[r] * 128 + cg * 64 + n * 16 + li];
        }
        float p = 0.f;
#pragma unroll
        for (int n = 0; n < 4; ++n) {
            v[r][n] = fmaxf(v[r][n], 0.f);
            p += v[r][n] * v[r][n];
        }
        p += __shfl_xor(p, 1);
        p += __shfl_xor(p, 2);
        p += __shfl_xor(p, 4);
        p += __shfl_xor(p, 8);
        if (li == 0) pnorm[cg * 64 + lr] = p;
    }
    __syncthreads();

#pragma unroll
    for (int r = 0; r < 4; ++r) {
        int lr = rg * 16 + kq * 4 + r;
        int grow = row0 + lr;
        float p = pnorm[lr] + pnorm[64 + lr];
        float sc = 1.0f / fmaxf(sqrtf(p), EPS);
        u16 vb[4];
#pragma unroll
        for (int n = 0; n < 4; ++n) vb[n] = f2bf(v[r][n] * sc);
        if (grow < N_NODES && biA[r] >= 0) {
#pragma unroll
            for (int n = 0; n < 4; ++n)
                H1g[(size_t)grow * 128 + cg * 64 + n * 16 + li] = vb[n];
        }
#pragma unroll
        for (int n = 0; n < 4; ++n) h1t[lr * 136 + cg * 64 + n * 16 + li] = vb[n];
    }
    __syncthreads();

    short8 af2[4];
#pragma unroll
    for (int kk = 0; kk < 4; ++kk)
        af2[kk] = *(const short8*)(h1t + lrow * 136 + kk * 32 + kq * 8);

    f32x4 m[4];
#pragma unroll
    for (int n = 0; n < 4; ++n) m[n] = (f32x4){0,0,0,0};
#pragma unroll
    for (int kk = 0; kk < 4; ++kk)
#pragma unroll
        for (int n = 0; n < 4; ++n) {
            int col = cg * 64 + n * 16 + li;
            short8 b = *(const short8*)(Wab + (size_t)col * 128 + kk * 32 + kq * 8);
            m[n] = __builtin_amdgcn_mfma_f32_16x16x32_bf16(af2[kk], b, m[n], 0, 0, 0);
        }

    float bav[4];
#pragma unroll
    for (int n = 0; n < 4; ++n) bav[n] = b_agg[cg * 64 + n * 16 + li];
#pragma unroll
    for (int r = 0; r < 4; ++r) {
        int grow = row0 + rg * 16 + kq * 4 + r;
        if (grow < N_NODES) {
#pragma unroll
            for (int n = 0; n < 4; ++n) {
                float t = m[n][r] + bav[n];
                t = t > 0.f ? t : 0.f;  // +0-safe relu (M1 feeds u16-max)
                M1[(size_t)grow * 128 + cg * 64 + n * 16 + li] = f2bf(t);
            }
        }
    }
}

// ---------------- tail gather: AB2[i] = [ H1[node_idx[i]] | max_nb M1[nb] ] (u16 max) ----------------
__global__ void tailg_k(const int* __restrict__ nbd, const int* __restrict__ node_idx,
                        const u16* __restrict__ H1g, const u16* __restrict__ M1,
                        u16* __restrict__ AB2) {
    int i = blockIdx.x;
    int t = threadIdx.x;  // 128
    __shared__ int nb[DEG];
    int n = node_idx[i];
    if (t < DEG) nb[t] = nbd[(size_t)n * 32 + t];
    AB2[(size_t)i * 256 + t] = H1g[(size_t)n * 128 + t];
    __syncthreads();
    u16 acc = 0;  // all M1 values >= +0
#pragma unroll
    for (int j = 0; j < DEG; ++j) {
        u16 v = M1[(size_t)nb[j] * 128 + t];
        acc = v > acc ? v : acc;
    }
    AB2[(size_t)i * 256 + 128 + t] = acc;
}

// ---------------- tail GEMM: out = norm(relu(AB2 @ W_lin.T + b_lin)), K=256 ----------------
__global__ __launch_bounds__(512) void tail_k(
    const u16* __restrict__ AB2, const u16* __restrict__ Wlb,
    const float* __restrict__ b_lin, float* __restrict__ out) {
    __shared__ float pn[128];
    __shared__ float pnt[16];
    int tid = threadIdx.x;
    int w = tid >> 6, l = tid & 63, li = l & 15, kq = l >> 4;
    int row0 = blockIdx.x * 16;
    int arow = row0 + li;
    int col = w * 16 + li;

    f32x4 acc = (f32x4){0,0,0,0};
#pragma unroll
    for (int kk = 0; kk < 8; ++kk) {
        short8 a = *(const short8*)(AB2 + (size_t)arow * 256 + kk * 32 + kq * 8);
        short8 b = *(const short8*)(Wlb + (size_t)col * 256 + kk * 32 + kq * 8);
        acc = __builtin_amdgcn_mfma_f32_16x16x32_bf16(a, b, acc, 0, 0, 0);
    }

    float bl = b_lin[col];
    float v[4];
#pragma unroll
    for (int r = 0; r < 4; ++r) {
        v[r] = fmaxf(acc[r] + bl, 0.f);
        float p = v[r] * v[r];
        p += __shfl_xor(p, 1);
        p += __shfl_xor(p, 2);
        p += __shfl_xor(p, 4);
        p += __shfl_xor(p, 8);
        if (li == 0) pn[w * 16 + kq * 4 + r] = p;
    }
    __syncthreads();
    if (tid < 16) {
        float s = 0.f;
#pragma unroll
        for (int ww = 0; ww < 8; ++ww) s += pn[ww * 16 + tid];
        pnt[tid] = s;
    }
    __syncthreads();
#pragma unroll
    for (int r = 0; r < 4; ++r) {
        int row = kq * 4 + r;
        float sc = 1.0f / fmaxf(sqrtf(pnt[row]), EPS);
        out[(size_t)(row0 + row) * 128 + col] = v[r] * sc;
    }
}

// ---------------- launch ----------------
extern "C" void kernel_launch(void* const* d_in, const int* in_sizes, int n_in,
                              void* d_out, int out_size, void* d_ws, size_t ws_size,
                              hipStream_t stream) {
    const int*   nbd      = (const int*)d_in[0];
    const int*   node_idx = (const int*)d_in[1];
    const float* feats    = (const float*)d_in[2];
    const float* W_agg    = (const float*)d_in[3];
    const float* b_agg    = (const float*)d_in[4];
    const float* W_lin    = (const float*)d_in[5];
    const float* b_lin    = (const float*)d_in[6];
    float* out = (float*)d_out;

    char* base = (char*)d_ws;
    size_t off = 0;
    int* inv       = (int*)(base + off);      off += 50048 * 4;
    u16* Wab       = (u16*)(base + off);      off += 16384 * 2;
    u16* Wlb       = (u16*)(base + off);      off += 32768 * 2;
    unsigned* rbap = (unsigned*)(base + off); off += 64 * 4;
    u16* M0b       = (u16*)(base + off);      off += (size_t)BATCH * 128 * 2;
    float* S       = (float*)(base + off);    off += (size_t)BATCH * 128 * 4;
    u16* AGG1      = (u16*)(base + off);      off += (size_t)N_NODES * 128 * 2;
    u16* H1g       = (u16*)(base + off);      off += (size_t)N_NODES * 128 * 2;
    u16* M1        = (u16*)(base + off);      off += (size_t)N_NODES * 128 * 2;
    u16* AB2       = (u16*)(base + off);      off += (size_t)BATCH * 256 * 2;

    prep_k<<<(50048 + 16384 + 32768 + 255) / 256, 256, 0, stream>>>(
        W_agg, W_lin, b_agg, inv, Wab, Wlb, rbap);

    head_k<<<BATCH / 16, 512, 0, stream>>>(feats, Wab, Wlb, b_agg, node_idx, inv, M0b, S);

    agg1_k<<<N_NODES / 4, 256, 0, stream>>>(nbd, inv, M0b, rbap, (unsigned*)AGG1);

    hop1mm_k<<<(N_NODES + 63) / 64, 512, 0, stream>>>(
        AGG1, inv, S, b_lin, b_agg, Wlb, Wab, H1g, M1);

    tailg_k<<<BATCH, 128, 0, stream>>>(nbd, node_idx, H1g, M1, AB2);

    tail_k<<<BATCH / 16, 512, 0, stream>>>(AB2, Wlb, b_lin, out);
}

// Round 7
// 84.371 us; speedup vs baseline: 1.6154x; 1.6154x over previous
//
#include <hip/hip_runtime.h>
#include <math.h>

#define N_NODES 50000
#define DEG 32
#define WIDTH 128
#define BATCH 4096
#define EPS 1e-12f

typedef __attribute__((ext_vector_type(8))) short short8;           // 8 bf16
typedef __attribute__((ext_vector_type(4))) float f32x4;            // MFMA acc
typedef unsigned short u16;

__device__ __forceinline__ u16 f2bf(float f) {
    unsigned x;
    __builtin_memcpy(&x, &f, 4);
    unsigned r = (x + 0x7fff + ((x >> 16) & 1)) >> 16;  // RNE
    return (u16)r;
}
__device__ __forceinline__ unsigned pkmax_u16(unsigned a, unsigned b) {
    unsigned lo = (a & 0xffffu) > (b & 0xffffu) ? (a & 0xffffu) : (b & 0xffffu);
    unsigned hi = (a >> 16) > (b >> 16) ? (a >> 16) : (b >> 16);
    return lo | (hi << 16);
}

// ---------------- prep: inv=-1, weights->bf16, packed relu(b_agg) ----------------
__global__ void prep_k(const float* __restrict__ W_agg, const float* __restrict__ W_lin,
                       const float* __restrict__ b_agg, int* __restrict__ inv,
                       u16* __restrict__ Wab, u16* __restrict__ Wlb,
                       unsigned* __restrict__ rbap) {
    int i = blockIdx.x * 256 + threadIdx.x;
    if (i < 50048) inv[i] = -1;
    int j = i - 50048;
    if (j >= 0 && j < 16384) Wab[j] = f2bf(W_agg[j]);
    int k = i - (50048 + 16384);
    if (k >= 0 && k < 32768) Wlb[k] = f2bf(W_lin[k]);
    if (i < 64) {
        float a = b_agg[2 * i], b = b_agg[2 * i + 1];
        a = a > 0.f ? a : 0.f;
        b = b > 0.f ? b : 0.f;
        rbap[i] = (unsigned)f2bf(a) | ((unsigned)f2bf(b) << 16);
    }
}

// ---------------- head: scatter inv; M0b(bf16)=relu(feats@Wagg.T+b_agg); S(f32)=feats@Wself.T
__global__ __launch_bounds__(512) void head_k(
    const float* __restrict__ feats, const u16* __restrict__ Wab, const u16* __restrict__ Wlb,
    const float* __restrict__ b_agg, const int* __restrict__ node_idx, int* __restrict__ inv,
    u16* __restrict__ M0b, float* __restrict__ S) {
    int tid = threadIdx.x;
    int gid = blockIdx.x * 512 + tid;
    if (gid < BATCH) atomicMax(&inv[node_idx[gid]], gid);  // last-write-wins scatter

    int w = tid >> 6, l = tid & 63, li = l & 15, kq = l >> 4;
    int r0 = blockIdx.x * 16;
    int arow = r0 + li;
    int col = w * 16 + li;

    f32x4 am = (f32x4){0,0,0,0}, as = (f32x4){0,0,0,0};
#pragma unroll
    for (int kk = 0; kk < 4; ++kk) {
        float4 a0 = *(const float4*)(feats + (size_t)arow * 128 + kk * 32 + kq * 8);
        float4 a1 = *(const float4*)(feats + (size_t)arow * 128 + kk * 32 + kq * 8 + 4);
        short8 a;
        a[0] = (short)f2bf(a0.x); a[1] = (short)f2bf(a0.y);
        a[2] = (short)f2bf(a0.z); a[3] = (short)f2bf(a0.w);
        a[4] = (short)f2bf(a1.x); a[5] = (short)f2bf(a1.y);
        a[6] = (short)f2bf(a1.z); a[7] = (short)f2bf(a1.w);
        short8 bm = *(const short8*)(Wab + (size_t)col * 128 + kk * 32 + kq * 8);
        am = __builtin_amdgcn_mfma_f32_16x16x32_bf16(a, bm, am, 0, 0, 0);
        short8 bs = *(const short8*)(Wlb + (size_t)col * 256 + kk * 32 + kq * 8);
        as = __builtin_amdgcn_mfma_f32_16x16x32_bf16(a, bs, as, 0, 0, 0);
    }

    float ba = b_agg[col];
#pragma unroll
    for (int r = 0; r < 4; ++r) {
        int grow = r0 + kq * 4 + r;
        float t = am[r] + ba;
        t = t > 0.f ? t : 0.f;               // +0-safe relu (feeds u16-max)
        M0b[(size_t)grow * 128 + col] = f2bf(t);
        S[(size_t)grow * 128 + col] = as[r];
    }
}

// ---------------- agg1 v2: one wave per TWO nodes; lane-parallel translate; shfl-broadcast gather ----------------
// AGG1[n] = max(warm: M0b[inv[nb]], anyCold: relu(b_agg)) in bf16/u16 packed domain.
__global__ __launch_bounds__(256) void agg1_k(
    const int* __restrict__ nbd, const int* __restrict__ inv,
    const u16* __restrict__ M0b, const unsigned* __restrict__ rbap,
    unsigned* __restrict__ AGG1u) {
    int wave = blockIdx.x * 4 + (threadIdx.x >> 6);  // 25000 waves, 2 nodes each
    int lane = threadIdx.x & 63;
    int n0 = wave * 2;

    // lane-parallel: 64 lanes cover both nodes' 32 neighbors each
    int nb = nbd[(size_t)n0 * DEG + lane];   // coalesced 256B
    int bi = inv[nb];                         // one vector gather, 64 lanes in flight
    unsigned long long warm = __ballot(bi >= 0);
    unsigned m0 = (unsigned)warm;             // node n0 (lanes 0..31)
    unsigned m1 = (unsigned)(warm >> 32);     // node n0+1 (lanes 32..63)

    unsigned rb = rbap[lane];                 // packed relu(b_agg), cols 2*lane..2*lane+1

    unsigned acc0 = (m0 != 0xffffffffu) ? rb : 0u;   // include cold base iff any cold
    while (m0) {
        int pos = __builtin_ctz(m0);
        m0 &= m0 - 1;
        int bib = __shfl(bi, pos);            // uniform broadcast -> SGPR base
        unsigned v = *(const unsigned*)(M0b + (size_t)bib * WIDTH) + 0;  // placeholder; replaced below
        v = ((const unsigned*)(M0b + (size_t)bib * WIDTH))[lane];
        acc0 = pkmax_u16(acc0, v);
    }
    AGG1u[(size_t)n0 * 64 + lane] = acc0;

    unsigned acc1 = (m1 != 0xffffffffu) ? rb : 0u;
    while (m1) {
        int pos = __builtin_ctz(m1);
        m1 &= m1 - 1;
        int bib = __shfl(bi, 32 + pos);
        unsigned v = ((const unsigned*)(M0b + (size_t)bib * WIDTH))[lane];
        acc1 = pkmax_u16(acc1, v);
    }
    AGG1u[(size_t)(n0 + 1) * 64 + lane] = acc1;
}

// ---------------- hop1mm: H1 = norm(relu(AGG1@Wlp.T + S[inv] + b_lin)); M1 = relu(H1@Wagg.T + b_agg)
__global__ __launch_bounds__(512) void hop1mm_k(
    const u16* __restrict__ AGG1, const int* __restrict__ inv,
    const float* __restrict__ S, const float* __restrict__ b_lin,
    const float* __restrict__ b_agg,
    const u16* __restrict__ Wlb, const u16* __restrict__ Wab,
    u16* __restrict__ H1g, u16* __restrict__ M1) {
    __shared__ u16 h1t[64 * 136];    // transpose buffer
    __shared__ float pnorm[2 * 64];  // [cg][row64]

    int tid = threadIdx.x;
    int w = tid >> 6, l = tid & 63, li = l & 15, kq = l >> 4;
    int rg = w >> 1, cg = w & 1;
    int row0 = blockIdx.x * 64;
    int lrow = rg * 16 + li;
    int arow = row0 + lrow;
    if (arow > N_NODES - 1) arow = N_NODES - 1;

    short8 af[4];
#pragma unroll
    for (int kk = 0; kk < 4; ++kk)
        af[kk] = *(const short8*)(AGG1 + (size_t)arow * 128 + kk * 32 + kq * 8);

    f32x4 h[4];
#pragma unroll
    for (int n = 0; n < 4; ++n) h[n] = (f32x4){0,0,0,0};
#pragma unroll
    for (int kk = 0; kk < 4; ++kk)
#pragma unroll
        for (int n = 0; n < 4; ++n) {
            int col = cg * 64 + n * 16 + li;
            short8 b = *(const short8*)(Wlb + (size_t)col * 256 + 128 + kk * 32 + kq * 8);
            h[n] = __builtin_amdgcn_mfma_f32_16x16x32_bf16(af[kk], b, h[n], 0, 0, 0);
        }

    float blv[4];
#pragma unroll
    for (int n = 0; n < 4; ++n) blv[n] = b_lin[cg * 64 + n * 16 + li];

    float v[4][4];   // [r][n] static-indexed
    int biA[4];
#pragma unroll
    for (int r = 0; r < 4; ++r) {
        int lr = rg * 16 + kq * 4 + r;
        int grow = row0 + lr;
        int growc = grow < N_NODES ? grow : N_NODES - 1;
        biA[r] = inv[growc];
#pragma unroll
        for (int n = 0; n < 4; ++n) v[r][n] = h[n][r] + blv[n];
        if (biA[r] >= 0) {
#pragma unroll
            for (int n = 0; n < 4; ++n)
                v[r][n] += S[(size_t)biA[r] * 128 + cg * 64 + n * 16 + li];
        }
        float p = 0.f;
#pragma unroll
        for (int n = 0; n < 4; ++n) {
            v[r][n] = fmaxf(v[r][n], 0.f);
            p += v[r][n] * v[r][n];
        }
        p += __shfl_xor(p, 1);
        p += __shfl_xor(p, 2);
        p += __shfl_xor(p, 4);
        p += __shfl_xor(p, 8);
        if (li == 0) pnorm[cg * 64 + lr] = p;
    }
    __syncthreads();

#pragma unroll
    for (int r = 0; r < 4; ++r) {
        int lr = rg * 16 + kq * 4 + r;
        int grow = row0 + lr;
        float p = pnorm[lr] + pnorm[64 + lr];
        float sc = 1.0f / fmaxf(sqrtf(p), EPS);
        u16 vb[4];
#pragma unroll
        for (int n = 0; n < 4; ++n) vb[n] = f2bf(v[r][n] * sc);
        if (grow < N_NODES && biA[r] >= 0) {
#pragma unroll
            for (int n = 0; n < 4; ++n)
                H1g[(size_t)grow * 128 + cg * 64 + n * 16 + li] = vb[n];
        }
#pragma unroll
        for (int n = 0; n < 4; ++n) h1t[lr * 136 + cg * 64 + n * 16 + li] = vb[n];
    }
    __syncthreads();

    short8 af2[4];
#pragma unroll
    for (int kk = 0; kk < 4; ++kk)
        af2[kk] = *(const short8*)(h1t + lrow * 136 + kk * 32 + kq * 8);

    f32x4 m[4];
#pragma unroll
    for (int n = 0; n < 4; ++n) m[n] = (f32x4){0,0,0,0};
#pragma unroll
    for (int kk = 0; kk < 4; ++kk)
#pragma unroll
        for (int n = 0; n < 4; ++n) {
            int col = cg * 64 + n * 16 + li;
            short8 b = *(const short8*)(Wab + (size_t)col * 128 + kk * 32 + kq * 8);
            m[n] = __builtin_amdgcn_mfma_f32_16x16x32_bf16(af2[kk], b, m[n], 0, 0, 0);
        }

    float bav[4];
#pragma unroll
    for (int n = 0; n < 4; ++n) bav[n] = b_agg[cg * 64 + n * 16 + li];
#pragma unroll
    for (int r = 0; r < 4; ++r) {
        int grow = row0 + rg * 16 + kq * 4 + r;
        if (grow < N_NODES) {
#pragma unroll
            for (int n = 0; n < 4; ++n) {
                float t = m[n][r] + bav[n];
                t = t > 0.f ? t : 0.f;  // +0-safe relu (M1 feeds u16-max)
                M1[(size_t)grow * 128 + cg * 64 + n * 16 + li] = f2bf(t);
            }
        }
    }
}

// ---------------- tailg v2: wave per batch row; AB2[i] = [ H1[node_idx[i]] | max_nb M1[nb] ] ----------------
__global__ __launch_bounds__(256) void tailg_k(
    const int* __restrict__ nbd, const int* __restrict__ node_idx,
    const u16* __restrict__ H1g, const u16* __restrict__ M1,
    unsigned* __restrict__ AB2u) {
    int i = blockIdx.x * 4 + (threadIdx.x >> 6);  // batch row, 1024*4 == 4096 exact
    int lane = threadIdx.x & 63;
    int n = node_idx[i];  // wave-uniform

    int nb = (lane < DEG) ? nbd[(size_t)n * DEG + lane] : 0;

    // first half: copy H1[n] (u32-packed)
    AB2u[(size_t)i * 128 + lane] = ((const unsigned*)(H1g + (size_t)n * 128))[lane];

    // second half: max over all 32 neighbors (independent loads, deep pipeline)
    unsigned acc = 0;  // all M1 values >= +0
#pragma unroll
    for (int j = 0; j < DEG; ++j) {
        int bib = __shfl(nb, j);
        unsigned v = ((const unsigned*)(M1 + (size_t)bib * 128))[lane];
        acc = pkmax_u16(acc, v);
    }
    AB2u[(size_t)i * 128 + 64 + lane] = acc;
}

// ---------------- tail GEMM: out = norm(relu(AB2 @ W_lin.T + b_lin)), K=256 ----------------
__global__ __launch_bounds__(512) void tail_k(
    const u16* __restrict__ AB2, const u16* __restrict__ Wlb,
    const float* __restrict__ b_lin, float* __restrict__ out) {
    __shared__ float pn[128];
    __shared__ float pnt[16];
    int tid = threadIdx.x;
    int w = tid >> 6, l = tid & 63, li = l & 15, kq = l >> 4;
    int row0 = blockIdx.x * 16;
    int arow = row0 + li;
    int col = w * 16 + li;

    f32x4 acc = (f32x4){0,0,0,0};
#pragma unroll
    for (int kk = 0; kk < 8; ++kk) {
        short8 a = *(const short8*)(AB2 + (size_t)arow * 256 + kk * 32 + kq * 8);
        short8 b = *(const short8*)(Wlb + (size_t)col * 256 + kk * 32 + kq * 8);
        acc = __builtin_amdgcn_mfma_f32_16x16x32_bf16(a, b, acc, 0, 0, 0);
    }

    float bl = b_lin[col];
    float v[4];
#pragma unroll
    for (int r = 0; r < 4; ++r) {
        v[r] = fmaxf(acc[r] + bl, 0.f);
        float p = v[r] * v[r];
        p += __shfl_xor(p, 1);
        p += __shfl_xor(p, 2);
        p += __shfl_xor(p, 4);
        p += __shfl_xor(p, 8);
        if (li == 0) pn[w * 16 + kq * 4 + r] = p;
    }
    __syncthreads();
    if (tid < 16) {
        float s = 0.f;
#pragma unroll
        for (int ww = 0; ww < 8; ++ww) s += pn[ww * 16 + tid];
        pnt[tid] = s;
    }
    __syncthreads();
#pragma unroll
    for (int r = 0; r < 4; ++r) {
        int row = kq * 4 + r;
        float sc = 1.0f / fmaxf(sqrtf(pnt[row]), EPS);
        out[(size_t)(row0 + row) * 128 + col] = v[r] * sc;
    }
}

// ---------------- launch ----------------
extern "C" void kernel_launch(void* const* d_in, const int* in_sizes, int n_in,
                              void* d_out, int out_size, void* d_ws, size_t ws_size,
                              hipStream_t stream) {
    const int*   nbd      = (const int*)d_in[0];
    const int*   node_idx = (const int*)d_in[1];
    const float* feats    = (const float*)d_in[2];
    const float* W_agg    = (const float*)d_in[3];
    const float* b_agg    = (const float*)d_in[4];
    const float* W_lin    = (const float*)d_in[5];
    const float* b_lin    = (const float*)d_in[6];
    float* out = (float*)d_out;

    char* base = (char*)d_ws;
    size_t off = 0;
    int* inv       = (int*)(base + off);      off += 50048 * 4;
    u16* Wab       = (u16*)(base + off);      off += 16384 * 2;
    u16* Wlb       = (u16*)(base + off);      off += 32768 * 2;
    unsigned* rbap = (unsigned*)(base + off); off += 64 * 4;
    u16* M0b       = (u16*)(base + off);      off += (size_t)BATCH * 128 * 2;
    float* S       = (float*)(base + off);    off += (size_t)BATCH * 128 * 4;
    u16* AGG1      = (u16*)(base + off);      off += (size_t)N_NODES * 128 * 2;
    u16* H1g       = (u16*)(base + off);      off += (size_t)N_NODES * 128 * 2;
    u16* M1        = (u16*)(base + off);      off += (size_t)N_NODES * 128 * 2;
    u16* AB2       = (u16*)(base + off);      off += (size_t)BATCH * 256 * 2;

    prep_k<<<(50048 + 16384 + 32768 + 255) / 256, 256, 0, stream>>>(
        W_agg, W_lin, b_agg, inv, Wab, Wlb, rbap);

    head_k<<<BATCH / 16, 512, 0, stream>>>(feats, Wab, Wlb, b_agg, node_idx, inv, M0b, S);

    agg1_k<<<N_NODES / 8, 256, 0, stream>>>(nbd, inv, M0b, rbap, (unsigned*)AGG1);

    hop1mm_k<<<(N_NODES + 63) / 64, 512, 0, stream>>>(
        AGG1, inv, S, b_lin, b_agg, Wlb, Wab, H1g, M1);

    tailg_k<<<BATCH / 4, 256, 0, stream>>>(nbd, node_idx, H1g, M1, (unsigned*)AB2);

    tail_k<<<BATCH / 16, 512, 0, stream>>>(AB2, Wlb, b_lin, out);
}

// Round 8
// 54.994 us; speedup vs baseline: 2.4783x; 1.5342x over previous
//
#include <hip/hip_runtime.h>
#include <math.h>

#define N_NODES 50000
#define DEG 32
#define WIDTH 128
#define BATCH 4096
#define EPS 1e-12f

typedef __attribute__((ext_vector_type(8))) short short8;           // 8 bf16
typedef __attribute__((ext_vector_type(4))) float f32x4;            // MFMA acc
typedef unsigned short u16;

__device__ __forceinline__ u16 f2bf(float f) {
    unsigned x;
    __builtin_memcpy(&x, &f, 4);
    unsigned r = (x + 0x7fff + ((x >> 16) & 1)) >> 16;  // RNE
    return (u16)r;
}
__device__ __forceinline__ unsigned pkmax_u16(unsigned a, unsigned b) {
    unsigned lo = (a & 0xffffu) > (b & 0xffffu) ? (a & 0xffffu) : (b & 0xffffu);
    unsigned hi = (a >> 16) > (b >> 16) ? (a >> 16) : (b >> 16);
    return lo | (hi << 16);
}

// ---------------- prep: inv=-1, weights->bf16, packed relu(b_agg) ----------------
__global__ void prep_k(const float* __restrict__ W_agg, const float* __restrict__ W_lin,
                       const float* __restrict__ b_agg, int* __restrict__ inv,
                       u16* __restrict__ Wab, u16* __restrict__ Wlb,
                       unsigned* __restrict__ rbap) {
    int i = blockIdx.x * 256 + threadIdx.x;
    if (i < 50048) inv[i] = -1;
    int j = i - 50048;
    if (j >= 0 && j < 16384) Wab[j] = f2bf(W_agg[j]);
    int k = i - (50048 + 16384);
    if (k >= 0 && k < 32768) Wlb[k] = f2bf(W_lin[k]);
    if (i < 64) {
        float a = b_agg[2 * i], b = b_agg[2 * i + 1];
        a = a > 0.f ? a : 0.f;
        b = b > 0.f ? b : 0.f;
        rbap[i] = (unsigned)f2bf(a) | ((unsigned)f2bf(b) << 16);
    }
}

// ---------------- head: scatter inv; M0b(bf16)=relu(feats@Wagg.T+b_agg); S(f32)=feats@Wself.T
__global__ __launch_bounds__(512) void head_k(
    const float* __restrict__ feats, const u16* __restrict__ Wab, const u16* __restrict__ Wlb,
    const float* __restrict__ b_agg, const int* __restrict__ node_idx, int* __restrict__ inv,
    u16* __restrict__ M0b, float* __restrict__ S) {
    int tid = threadIdx.x;
    int gid = blockIdx.x * 512 + tid;
    if (gid < BATCH) atomicMax(&inv[node_idx[gid]], gid);  // last-write-wins scatter

    int w = tid >> 6, l = tid & 63, li = l & 15, kq = l >> 4;
    int r0 = blockIdx.x * 16;
    int arow = r0 + li;
    int col = w * 16 + li;

    f32x4 am = (f32x4){0,0,0,0}, as = (f32x4){0,0,0,0};
#pragma unroll
    for (int kk = 0; kk < 4; ++kk) {
        float4 a0 = *(const float4*)(feats + (size_t)arow * 128 + kk * 32 + kq * 8);
        float4 a1 = *(const float4*)(feats + (size_t)arow * 128 + kk * 32 + kq * 8 + 4);
        short8 a;
        a[0] = (short)f2bf(a0.x); a[1] = (short)f2bf(a0.y);
        a[2] = (short)f2bf(a0.z); a[3] = (short)f2bf(a0.w);
        a[4] = (short)f2bf(a1.x); a[5] = (short)f2bf(a1.y);
        a[6] = (short)f2bf(a1.z); a[7] = (short)f2bf(a1.w);
        short8 bm = *(const short8*)(Wab + (size_t)col * 128 + kk * 32 + kq * 8);
        am = __builtin_amdgcn_mfma_f32_16x16x32_bf16(a, bm, am, 0, 0, 0);
        short8 bs = *(const short8*)(Wlb + (size_t)col * 256 + kk * 32 + kq * 8);
        as = __builtin_amdgcn_mfma_f32_16x16x32_bf16(a, bs, as, 0, 0, 0);
    }

    float ba = b_agg[col];
#pragma unroll
    for (int r = 0; r < 4; ++r) {
        int grow = r0 + kq * 4 + r;
        float t = am[r] + ba;
        t = t > 0.f ? t : 0.f;               // +0-safe relu (feeds u16-max)
        M0b[(size_t)grow * 128 + col] = f2bf(t);
        S[(size_t)grow * 128 + col] = as[r];
    }
}

// ---------------- agg1: one wave per TWO nodes; lane-parallel translate; shfl-broadcast gather ----------------
__global__ __launch_bounds__(256) void agg1_k(
    const int* __restrict__ nbd, const int* __restrict__ inv,
    const u16* __restrict__ M0b, const unsigned* __restrict__ rbap,
    unsigned* __restrict__ AGG1u) {
    int wave = blockIdx.x * 4 + (threadIdx.x >> 6);  // 25000 waves, 2 nodes each
    int lane = threadIdx.x & 63;
    int n0 = wave * 2;

    int nb = nbd[(size_t)n0 * DEG + lane];   // coalesced 256B (covers both nodes)
    int bi = inv[nb];                         // one vector gather, 64 lanes in flight
    unsigned long long warm = __ballot(bi >= 0);
    unsigned m0 = (unsigned)warm;             // node n0 (lanes 0..31)
    unsigned m1 = (unsigned)(warm >> 32);     // node n0+1 (lanes 32..63)

    unsigned rb = rbap[lane];                 // packed relu(b_agg)

    unsigned acc0 = (m0 != 0xffffffffu) ? rb : 0u;
    while (m0) {
        int pos = __builtin_ctz(m0);
        m0 &= m0 - 1;
        int bib = __shfl(bi, pos);
        unsigned v = ((const unsigned*)(M0b + (size_t)bib * WIDTH))[lane];
        acc0 = pkmax_u16(acc0, v);
    }
    AGG1u[(size_t)n0 * 64 + lane] = acc0;

    unsigned acc1 = (m1 != 0xffffffffu) ? rb : 0u;
    while (m1) {
        int pos = __builtin_ctz(m1);
        m1 &= m1 - 1;
        int bib = __shfl(bi, 32 + pos);
        unsigned v = ((const unsigned*)(M0b + (size_t)bib * WIDTH))[lane];
        acc1 = pkmax_u16(acc1, v);
    }
    AGG1u[(size_t)(n0 + 1) * 64 + lane] = acc1;
}

// ---------------- hop1mm v3: W staged in LDS (XOR-swizzled), 128-row tiles, full-row waves ----------------
// H1 = norm(relu(AGG1@Wlp.T + S[inv] + b_lin));  M1 = relu(H1@Wagg.T + b_agg)
__global__ __launch_bounds__(512) void hop1mm_k(
    const u16* __restrict__ AGG1, const int* __restrict__ inv,
    const float* __restrict__ S, const float* __restrict__ b_lin,
    const float* __restrict__ b_agg,
    const u16* __restrict__ Wlb, const u16* __restrict__ Wab,
    u16* __restrict__ H1g, u16* __restrict__ M1) {
    __shared__ u16 wlds[128 * 128];   // 32KB swizzled W (Wlp phase1, Wab phase2)
    __shared__ u16 h1t[128 * 136];    // 34.8KB transpose buffer (pad 8 u16)

    int tid = threadIdx.x;
    int w = tid >> 6, l = tid & 63, li = l & 15, kq = l >> 4;
    int row0 = blockIdx.x * 128;
    int lrow = w * 16 + li;           // A-frag row (wave owns 16 full rows)
    int arow = row0 + lrow;
    if (arow > N_NODES - 1) arow = N_NODES - 1;

    // issue A-frag loads early (hide under W staging)
    short8 af[4];
#pragma unroll
    for (int kk = 0; kk < 4; ++kk)
        af[kk] = *(const short8*)(AGG1 + (size_t)arow * 128 + kk * 32 + kq * 8);

    // stage Wlp (k-cols 128..255 of Wlb) into LDS, XOR-swizzled rows
#pragma unroll
    for (int it = 0; it < 4; ++it) {
        int c = tid + it * 512;            // 16B chunk id, 0..2047
        int r = c >> 4;                    // W row (= output col), 0..127
        int cb = (c & 15) << 4;            // byte offset within 256B k-row
        short8 v = *(const short8*)(Wlb + (size_t)r * 256 + 128 + ((c & 15) << 3));
        *(short8*)((char*)wlds + r * 256 + (cb ^ ((r & 7) << 4))) = v;
    }
    __syncthreads();

    // GEMM1: h = AGG1 @ Wlp.T   (B from swizzled LDS: 2-way banks = free)
    f32x4 h[8];
#pragma unroll
    for (int n = 0; n < 8; ++n) h[n] = (f32x4){0,0,0,0};
#pragma unroll
    for (int kk = 0; kk < 4; ++kk)
#pragma unroll
        for (int n = 0; n < 8; ++n) {
            int col = n * 16 + li;
            short8 b = *(const short8*)((char*)wlds + col * 256 +
                                        ((kk * 64 + kq * 16) ^ ((col & 7) << 4)));
            h[n] = __builtin_amdgcn_mfma_f32_16x16x32_bf16(af[kk], b, h[n], 0, 0, 0);
        }

    // epilogue 1: +S[inv], +b_lin, relu, wave-internal row-norm; write warm H1; stash h1t
    float blv[8];
#pragma unroll
    for (int n = 0; n < 8; ++n) blv[n] = b_lin[n * 16 + li];

#pragma unroll
    for (int r = 0; r < 4; ++r) {
        int lr = w * 16 + kq * 4 + r;
        int grow = row0 + lr;
        int growc = grow < N_NODES ? grow : N_NODES - 1;
        int bi = inv[growc];
        float v[8];
#pragma unroll
        for (int n = 0; n < 8; ++n) v[n] = h[n][r] + blv[n];
        if (bi >= 0) {
#pragma unroll
            for (int n = 0; n < 8; ++n) v[n] += S[(size_t)bi * 128 + n * 16 + li];
        }
        float p = 0.f;
#pragma unroll
        for (int n = 0; n < 8; ++n) {
            v[n] = fmaxf(v[n], 0.f);
            p += v[n] * v[n];
        }
        p += __shfl_xor(p, 1);
        p += __shfl_xor(p, 2);
        p += __shfl_xor(p, 4);
        p += __shfl_xor(p, 8);
        float sc = 1.0f / fmaxf(sqrtf(p), EPS);
        u16 vb[8];
#pragma unroll
        for (int n = 0; n < 8; ++n) vb[n] = f2bf(v[n] * sc);
        if (grow < N_NODES && bi >= 0) {
#pragma unroll
            for (int n = 0; n < 8; ++n) H1g[(size_t)grow * 128 + n * 16 + li] = vb[n];
        }
#pragma unroll
        for (int n = 0; n < 8; ++n) h1t[lr * 136 + n * 16 + li] = vb[n];
    }
    __syncthreads();   // GEMM1 B-reads + h1t writes complete

    // restage W: Wab (full 128 k-cols), overwrites wlds
#pragma unroll
    for (int it = 0; it < 4; ++it) {
        int c = tid + it * 512;
        int r = c >> 4;
        int cb = (c & 15) << 4;
        short8 v = *(const short8*)(Wab + (size_t)r * 128 + ((c & 15) << 3));
        *(short8*)((char*)wlds + r * 256 + (cb ^ ((r & 7) << 4))) = v;
    }
    __syncthreads();

    // GEMM2: M1 = relu(H1 @ Wagg.T + b_agg);  A from h1t (2-way banks)
    short8 af2[4];
#pragma unroll
    for (int kk = 0; kk < 4; ++kk)
        af2[kk] = *(const short8*)(h1t + lrow * 136 + kk * 32 + kq * 8);

    f32x4 m[8];
#pragma unroll
    for (int n = 0; n < 8; ++n) m[n] = (f32x4){0,0,0,0};
#pragma unroll
    for (int kk = 0; kk < 4; ++kk)
#pragma unroll
        for (int n = 0; n < 8; ++n) {
            int col = n * 16 + li;
            short8 b = *(const short8*)((char*)wlds + col * 256 +
                                        ((kk * 64 + kq * 16) ^ ((col & 7) << 4)));
            m[n] = __builtin_amdgcn_mfma_f32_16x16x32_bf16(af2[kk], b, m[n], 0, 0, 0);
        }

    float bav[8];
#pragma unroll
    for (int n = 0; n < 8; ++n) bav[n] = b_agg[n * 16 + li];
#pragma unroll
    for (int r = 0; r < 4; ++r) {
        int grow = row0 + w * 16 + kq * 4 + r;
        if (grow < N_NODES) {
#pragma unroll
            for (int n = 0; n < 8; ++n) {
                float t = m[n][r] + bav[n];
                t = t > 0.f ? t : 0.f;  // +0-safe relu (M1 feeds u16-max)
                M1[(size_t)grow * 128 + n * 16 + li] = f2bf(t);
            }
        }
    }
}

// ---------------- tail fused: gather [H1 | max M1] into LDS, then K=256 GEMM + norm ----------------
// 256 blocks x 512 thr (8 waves); block owns 16 batch rows; wave w gathers rows 2w,2w+1.
__global__ __launch_bounds__(512) void tail_k(
    const int* __restrict__ nbd, const int* __restrict__ node_idx,
    const u16* __restrict__ H1g, const u16* __restrict__ M1,
    const u16* __restrict__ Wlb, const float* __restrict__ b_lin,
    float* __restrict__ out) {
    __shared__ u16 ab2[16 * 264];    // 16 rows x (256 + 8 pad) u16
    __shared__ float pn[128];
    __shared__ float pnt[16];

    int tid = threadIdx.x;
    int w = tid >> 6, l = tid & 63, li = l & 15, kq = l >> 4;
    int row0 = blockIdx.x * 16;

    // gather phase
#pragma unroll
    for (int rr = 0; rr < 2; ++rr) {
        int lr = w * 2 + rr;
        int i = row0 + lr;
        int n = node_idx[i];  // wave-uniform
        unsigned hv = ((const unsigned*)(H1g + (size_t)n * 128))[l];
        *(unsigned*)((char*)ab2 + lr * 528 + l * 4) = hv;
        int nb = (l < DEG) ? nbd[(size_t)n * DEG + l] : 0;
        unsigned acc = 0;  // all M1 values >= +0
#pragma unroll
        for (int j = 0; j < DEG; ++j) {
            int bib = __shfl(nb, j);
            unsigned v = ((const unsigned*)(M1 + (size_t)bib * 128))[l];
            acc = pkmax_u16(acc, v);
        }
        *(unsigned*)((char*)ab2 + lr * 528 + 256 + l * 4) = acc;
    }
    __syncthreads();

    // GEMM: out cols w*16+li, K=256; A from LDS (2-way banks), B from L2
    int col = w * 16 + li;
    f32x4 acc4 = (f32x4){0,0,0,0};
#pragma unroll
    for (int kk = 0; kk < 8; ++kk) {
        short8 a = *(const short8*)((char*)ab2 + li * 528 + kk * 64 + kq * 16);
        short8 b = *(const short8*)(Wlb + (size_t)col * 256 + kk * 32 + kq * 8);
        acc4 = __builtin_amdgcn_mfma_f32_16x16x32_bf16(a, b, acc4, 0, 0, 0);
    }

    float bl = b_lin[col];
    float v[4];
#pragma unroll
    for (int r = 0; r < 4; ++r) {
        v[r] = fmaxf(acc4[r] + bl, 0.f);
        float p = v[r] * v[r];
        p += __shfl_xor(p, 1);
        p += __shfl_xor(p, 2);
        p += __shfl_xor(p, 4);
        p += __shfl_xor(p, 8);
        if (li == 0) pn[w * 16 + kq * 4 + r] = p;
    }
    __syncthreads();
    if (tid < 16) {
        float s = 0.f;
#pragma unroll
        for (int ww = 0; ww < 8; ++ww) s += pn[ww * 16 + tid];
        pnt[tid] = s;
    }
    __syncthreads();
#pragma unroll
    for (int r = 0; r < 4; ++r) {
        int row = kq * 4 + r;
        float sc = 1.0f / fmaxf(sqrtf(pnt[row]), EPS);
        out[(size_t)(row0 + row) * 128 + col] = v[r] * sc;
    }
}

// ---------------- launch ----------------
extern "C" void kernel_launch(void* const* d_in, const int* in_sizes, int n_in,
                              void* d_out, int out_size, void* d_ws, size_t ws_size,
                              hipStream_t stream) {
    const int*   nbd      = (const int*)d_in[0];
    const int*   node_idx = (const int*)d_in[1];
    const float* feats    = (const float*)d_in[2];
    const float* W_agg    = (const float*)d_in[3];
    const float* b_agg    = (const float*)d_in[4];
    const float* W_lin    = (const float*)d_in[5];
    const float* b_lin    = (const float*)d_in[6];
    float* out = (float*)d_out;

    char* base = (char*)d_ws;
    size_t off = 0;
    int* inv       = (int*)(base + off);      off += 50048 * 4;
    u16* Wab       = (u16*)(base + off);      off += 16384 * 2;
    u16* Wlb       = (u16*)(base + off);      off += 32768 * 2;
    unsigned* rbap = (unsigned*)(base + off); off += 64 * 4;
    u16* M0b       = (u16*)(base + off);      off += (size_t)BATCH * 128 * 2;
    float* S       = (float*)(base + off);    off += (size_t)BATCH * 128 * 4;
    u16* AGG1      = (u16*)(base + off);      off += (size_t)N_NODES * 128 * 2;
    u16* H1g       = (u16*)(base + off);      off += (size_t)N_NODES * 128 * 2;
    u16* M1        = (u16*)(base + off);      off += (size_t)N_NODES * 128 * 2;

    prep_k<<<(50048 + 16384 + 32768 + 255) / 256, 256, 0, stream>>>(
        W_agg, W_lin, b_agg, inv, Wab, Wlb, rbap);

    head_k<<<BATCH / 16, 512, 0, stream>>>(feats, Wab, Wlb, b_agg, node_idx, inv, M0b, S);

    agg1_k<<<N_NODES / 8, 256, 0, stream>>>(nbd, inv, M0b, rbap, (unsigned*)AGG1);

    hop1mm_k<<<(N_NODES + 127) / 128, 512, 0, stream>>>(
        AGG1, inv, S, b_lin, b_agg, Wlb, Wab, H1g, M1);

    tail_k<<<BATCH / 16, 512, 0, stream>>>(nbd, node_idx, H1g, M1, Wlb, b_lin, out);
}